// Round 5
// baseline (831.843 us; speedup 1.0000x reference)
//
#include <hip/hip_runtime.h>
#include <hip/hip_bf16.h>
#include <stdint.h>

#define TOKENS 4096
#define IN_F   4096
#define OUT_F  11008
#define NGROUPS 32

typedef __bf16 bf16_t;
typedef __bf16 bf16x4 __attribute__((ext_vector_type(4)));
typedef __bf16 bf16x8 __attribute__((ext_vector_type(8)));
typedef float  f32x4  __attribute__((ext_vector_type(4)));

// ---------------- fused pre-pass: x cvt + W dequant in one launch ----------
#define XBLK (TOKENS * IN_F / (4 * 256))   // 16384
#define WBLK (OUT_F * IN_F / (4 * 256))    // 44032

__global__ __launch_bounds__(256)
void prep_kernel(const float* __restrict__ x, bf16_t* __restrict__ xb,
                 const int* __restrict__ w, const float* __restrict__ scale,
                 bf16_t* __restrict__ wb) {
    int b = blockIdx.x;
    if (b < XBLK) {
        int v = b * 256 + threadIdx.x;               // one float4 per thread
        float4 a = ((const float4*)x)[v];
        bf16x4 o;
        o[0] = (bf16_t)a.x; o[1] = (bf16_t)a.y; o[2] = (bf16_t)a.z; o[3] = (bf16_t)a.w;
        ((bf16x4*)xb)[v] = o;
    } else {
        int v = (b - XBLK) * 256 + threadIdx.x;      // one int4 (4 weights)
        int4 a = ((const int4*)w)[v];
        float s = scale[(v >> 10) * NGROUPS + ((v & 1023) >> 5)];
        bf16x4 o;
        o[0] = (bf16_t)((float)a.x * s);
        o[1] = (bf16_t)((float)a.y * s);
        o[2] = (bf16_t)((float)a.z * s);
        o[3] = (bf16_t)((float)a.w * s);
        ((bf16x4*)wb)[v] = o;
    }
}

// ---------------- GEMM: C = A[M,K] * B[N,K]^T + bias ----------------
// 256x256 tile, BK=32, 8 waves (2M x 4N), wave tile 128x64, 4-slot LDS ring.
// Schedule (round-5): ONE barrier per chunk, counted vmcnt(4), counted
// lgkmcnt(2/2/2/6) (never 0 in loop), 4 MFMA clusters of 8 with ds_reads
// for later sections interleaved under each cluster's shadow. Fragment
// registers roll: A-pairs ping-pong pa/pb; bF + next-chunk bF'/P0' read
// under C2/C3. Waitcnt ledger (per wave, DS FIFO):
//   enter chunk j: outstanding = {bF(j) x4, P0(j) x2}
//   read P1 -> out 8 ; lgkmcnt(2) drains bF,P0 ; C0 (P0 x bF)
//   read P2 -> out 4 ; lgkmcnt(2) drains P1    ; C1 (P1 x bF)
//   read P3 -> out 4 ; lgkmcnt(2) drains P2    ; C2 (P2 x bF)
//   read bF',P0' -> 8; lgkmcnt(6) drains P3    ; C3 (P3 x bF)
// Stages: 4 async16/chunk at top; vmcnt(4) before the barrier drains
// S_{j-2} -> slot j+1 certified for this chunk's bF'/P0' reads.
// WAR: S_j writes slot (j-1)&3; all reads of slot j-1 drained by the
// lgkmcnt chain of chunk j-1 before the top-of-j barrier.
#define BM 256
#define BN 256
#define BK 32
#define NCH   (IN_F / BK)    // 128
#define SLOTE (BM * BK)      // 8192 bf16 = 16 KiB per ring slot
#define NT_M  (TOKENS / BM)  // 16
#define NT_N  (OUT_F / BN)   // 43

__device__ __forceinline__ void async16(const void* g, void* l) {
    __builtin_amdgcn_global_load_lds(
        (const __attribute__((address_space(1))) uint32_t*)g,
        (__attribute__((address_space(3))) uint32_t*)l, 16, 0, 0);
}

#define MFMA(d, a, b) d = __builtin_amdgcn_mfma_f32_16x16x32_bf16(a, b, d, 0, 0, 0)

__global__ __launch_bounds__(512, 2)
void gemm_bt_kernel(const bf16_t* __restrict__ A,
                    const bf16_t* __restrict__ B,
                    const float* __restrict__ bias,
                    float* __restrict__ C) {
    __shared__ __align__(16) bf16_t sA[4 * SLOTE];
    __shared__ __align__(16) bf16_t sB[4 * SLOTE];

    // ---- XCD-rectangle walk (round-4; FETCH -32%): grid 704 = 8 x 88 ----
    const int lin = blockIdx.x;
    const int xcd = lin & 7;
    const int idx = lin >> 3;
    const int mg  = xcd >> 1;
    const int nh  = xcd & 1;
    if (nh && idx >= 84) return;
    int ml, nl;
    const int s  = idx >> 5;
    if (s < 2) { ml = (idx >> 3) & 3; nl = idx & 7; }
    else {
        const int w  = nh ? 5 : 6;
        const int lo = idx - 64;
        ml = lo / w; nl = lo - ml * w;
    }
    const int bm = (mg * 4 + ml) * BM;
    const int bn = ((nh ? 22 : 0) + s * 8 + nl) * BN;

    const int tid    = threadIdx.x;
    const int lane   = tid & 63;
    const int wave   = tid >> 6;
    const int wm     = wave >> 2;
    const int wn     = wave & 3;
    const int lane15 = lane & 15;
    const int quad   = lane >> 4;
    const int swq    = quad ^ ((lane15 >> 1) & 3);   // conflict-free (r3-verified)

    int aoff[8], boff[4];
    #pragma unroll
    for (int i = 0; i < 8; ++i) {
        int mr = wm * 128 + i * 16 + lane15;
        aoff[i] = mr * BK + swq * 8;
    }
    #pragma unroll
    for (int t = 0; t < 4; ++t) {
        int nr = wn * 64 + t * 16 + lane15;
        boff[t] = nr * BK + swq * 8;
    }

    const int r0   = tid >> 2;
    const int qlog = (tid & 3) ^ ((tid >> 3) & 3);
    const bf16_t* gA0 = A + (size_t)(bm + r0) * IN_F + qlog * 8;
    const bf16_t* gA1 = A + (size_t)(bm + 128 + r0) * IN_F + qlog * 8;
    const bf16_t* gB0 = B + (size_t)(bn + r0) * IN_F + qlog * 8;
    const bf16_t* gB1 = B + (size_t)(bn + 128 + r0) * IN_F + qlog * 8;
    const int ldsP0 = wave * 512;
    const int ldsP1 = 4096 + wave * 512;

    f32x4 acc[8][4] = {};

    // prologue: stage slots 0,1,2 (12 loads); certify slot 0; read bF(0),P0(0)
    #pragma unroll
    for (int c = 0; c < 3; ++c) {
        async16(gA0 + c * BK, sA + c * SLOTE + ldsP0);
        async16(gA1 + c * BK, sA + c * SLOTE + ldsP1);
        async16(gB0 + c * BK, sB + c * SLOTE + ldsP0);
        async16(gB1 + c * BK, sB + c * SLOTE + ldsP1);
    }
    asm volatile("s_waitcnt vmcnt(8)" ::: "memory");   // slot 0 landed
    __builtin_amdgcn_s_barrier();
    __builtin_amdgcn_sched_barrier(0);

    bf16x8 bF0 = *(const bf16x8*)(sB + boff[0]);
    bf16x8 bF1 = *(const bf16x8*)(sB + boff[1]);
    bf16x8 bF2 = *(const bf16x8*)(sB + boff[2]);
    bf16x8 bF3 = *(const bf16x8*)(sB + boff[3]);
    bf16x8 pa0 = *(const bf16x8*)(sA + aoff[0]);
    bf16x8 pa1 = *(const bf16x8*)(sA + aoff[1]);

    for (int j = 0; j < NCH; ++j) {
        const bf16_t* sAs = sA + (j & 3) * SLOTE;          // slot j
        const bf16_t* sAn = sA + ((j + 1) & 3) * SLOTE;    // slot j+1
        const bf16_t* sBn = sB + ((j + 1) & 3) * SLOTE;
        const int cs   = j + 3;
        const int kpre = (cs < NCH ? cs : NCH - 1) * BK;   // clamp: dummy
        bf16_t* dA = sA + (cs & 3) * SLOTE;
        bf16_t* dB = sB + (cs & 3) * SLOTE;

        // ---- top: certify slot j+1 (S_{j-2}), rendezvous, stage slot j+3
        asm volatile("s_waitcnt vmcnt(4)" ::: "memory");
        __builtin_amdgcn_s_barrier();
        __builtin_amdgcn_sched_barrier(0);
        async16(gA0 + kpre, dA + ldsP0);
        async16(gA1 + kpre, dA + ldsP1);
        async16(gB0 + kpre, dB + ldsP0);
        async16(gB1 + kpre, dB + ldsP1);

        // ---- sec0: read P1 -> pb; drain bF,P0; C0 = P0 x bF
        bf16x8 pb0 = *(const bf16x8*)(sAs + aoff[2]);
        bf16x8 pb1 = *(const bf16x8*)(sAs + aoff[3]);
        asm volatile("s_waitcnt lgkmcnt(2)" ::: "memory");
        __builtin_amdgcn_sched_barrier(0);
        __builtin_amdgcn_s_setprio(1);
        MFMA(acc[0][0], pa0, bF0); MFMA(acc[0][1], pa0, bF1);
        MFMA(acc[0][2], pa0, bF2); MFMA(acc[0][3], pa0, bF3);
        MFMA(acc[1][0], pa1, bF0); MFMA(acc[1][1], pa1, bF1);
        MFMA(acc[1][2], pa1, bF2); MFMA(acc[1][3], pa1, bF3);
        __builtin_amdgcn_s_setprio(0);

        // ---- sec1: read P2 -> pa; drain P1; C1 = P1 x bF
        pa0 = *(const bf16x8*)(sAs + aoff[4]);
        pa1 = *(const bf16x8*)(sAs + aoff[5]);
        asm volatile("s_waitcnt lgkmcnt(2)" ::: "memory");
        __builtin_amdgcn_sched_barrier(0);
        __builtin_amdgcn_s_setprio(1);
        MFMA(acc[2][0], pb0, bF0); MFMA(acc[2][1], pb0, bF1);
        MFMA(acc[2][2], pb0, bF2); MFMA(acc[2][3], pb0, bF3);
        MFMA(acc[3][0], pb1, bF0); MFMA(acc[3][1], pb1, bF1);
        MFMA(acc[3][2], pb1, bF2); MFMA(acc[3][3], pb1, bF3);
        __builtin_amdgcn_s_setprio(0);

        // ---- sec2: read P3 -> pb; drain P2; C2 = P2 x bF
        pb0 = *(const bf16x8*)(sAs + aoff[6]);
        pb1 = *(const bf16x8*)(sAs + aoff[7]);
        asm volatile("s_waitcnt lgkmcnt(2)" ::: "memory");
        __builtin_amdgcn_sched_barrier(0);
        __builtin_amdgcn_s_setprio(1);
        MFMA(acc[4][0], pa0, bF0); MFMA(acc[4][1], pa0, bF1);
        MFMA(acc[4][2], pa0, bF2); MFMA(acc[4][3], pa0, bF3);
        MFMA(acc[5][0], pa1, bF0); MFMA(acc[5][1], pa1, bF1);
        MFMA(acc[5][2], pa1, bF2); MFMA(acc[5][3], pa1, bF3);
        __builtin_amdgcn_s_setprio(0);

        // ---- sec3: read bF'(j+1), P0'(j+1); drain P3; C3 = P3 x bF
        bf16x8 nb0 = *(const bf16x8*)(sBn + boff[0]);
        bf16x8 nb1 = *(const bf16x8*)(sBn + boff[1]);
        bf16x8 nb2 = *(const bf16x8*)(sBn + boff[2]);
        bf16x8 nb3 = *(const bf16x8*)(sBn + boff[3]);
        bf16x8 na0 = *(const bf16x8*)(sAn + aoff[0]);
        bf16x8 na1 = *(const bf16x8*)(sAn + aoff[1]);
        asm volatile("s_waitcnt lgkmcnt(6)" ::: "memory");
        __builtin_amdgcn_sched_barrier(0);
        __builtin_amdgcn_s_setprio(1);
        MFMA(acc[6][0], pb0, bF0); MFMA(acc[6][1], pb0, bF1);
        MFMA(acc[6][2], pb0, bF2); MFMA(acc[6][3], pb0, bF3);
        MFMA(acc[7][0], pb1, bF0); MFMA(acc[7][1], pb1, bF1);
        MFMA(acc[7][2], pb1, bF2); MFMA(acc[7][3], pb1, bF3);
        __builtin_amdgcn_s_setprio(0);

        // carry next chunk's fragments
        bF0 = nb0; bF1 = nb1; bF2 = nb2; bF3 = nb3;
        pa0 = na0; pa1 = na1;
    }

    // keep last-iteration carried loads live (DCE would corrupt the
    // lgkmcnt ledger of the final chunk — rule #17)
    asm volatile("" :: "v"((float)bF0[0]), "v"((float)bF1[0]),
                       "v"((float)bF2[0]), "v"((float)bF3[0]),
                       "v"((float)pa0[0]), "v"((float)pa1[0]));

    // drain all in-flight ops before LDS goes dead / epilogue runs
    asm volatile("s_waitcnt vmcnt(0) lgkmcnt(0)" ::: "memory");

    // epilogue: C/D layout col=lane&15, row=quad*4+reg (m89/m91-verified)
    #pragma unroll
    for (int t = 0; t < 4; ++t) {
        const int n = bn + wn * 64 + t * 16 + lane15;
        const float bj = bias[n];
        #pragma unroll
        for (int i = 0; i < 8; ++i) {
            const int m0 = bm + wm * 128 + i * 16 + quad * 4;
            #pragma unroll
            for (int r = 0; r < 4; ++r)
                C[(size_t)(m0 + r) * OUT_F + n] = acc[i][t][r] + bj;
        }
    }
}

extern "C" void kernel_launch(void* const* d_in, const int* in_sizes, int n_in,
                              void* d_out, int out_size, void* d_ws, size_t ws_size,
                              hipStream_t stream) {
    const float* x     = (const float*)d_in[0];
    const int*   w     = (const int*)d_in[1];
    const float* scale = (const float*)d_in[2];
    const float* bias  = (const float*)d_in[3];
    float* out = (float*)d_out;

    bf16_t* xb = (bf16_t*)d_ws;
    bf16_t* wb = (bf16_t*)((char*)d_ws + (size_t)TOKENS * IN_F * 2);

    prep_kernel<<<XBLK + WBLK, 256, 0, stream>>>(x, xb, w, scale, wb);
    gemm_bt_kernel<<<704, 512, 0, stream>>>(xb, wb, bias, out);
}

// Round 6
// 685.666 us; speedup vs baseline: 1.2132x; 1.2132x over previous
//
#include <hip/hip_runtime.h>
#include <hip/hip_bf16.h>
#include <stdint.h>

#define TOKENS 4096
#define IN_F   4096
#define OUT_F  11008
#define NGROUPS 32

typedef __bf16 bf16_t;
typedef __bf16 bf16x4 __attribute__((ext_vector_type(4)));
typedef __bf16 bf16x8 __attribute__((ext_vector_type(8)));
typedef float  f32x4  __attribute__((ext_vector_type(4)));

// ---------------- fused pre-pass: x cvt + W dequant in one launch ----------
#define XBLK (TOKENS * IN_F / (4 * 256))   // 16384
#define WBLK (OUT_F * IN_F / (4 * 256))    // 44032

__global__ __launch_bounds__(256)
void prep_kernel(const float* __restrict__ x, bf16_t* __restrict__ xb,
                 const int* __restrict__ w, const float* __restrict__ scale,
                 bf16_t* __restrict__ wb) {
    int b = blockIdx.x;
    if (b < XBLK) {
        int v = b * 256 + threadIdx.x;               // one float4 per thread
        float4 a = ((const float4*)x)[v];
        bf16x4 o;
        o[0] = (bf16_t)a.x; o[1] = (bf16_t)a.y; o[2] = (bf16_t)a.z; o[3] = (bf16_t)a.w;
        ((bf16x4*)xb)[v] = o;
    } else {
        int v = (b - XBLK) * 256 + threadIdx.x;      // one int4 (4 weights)
        int4 a = ((const int4*)w)[v];
        float s = scale[(v >> 10) * NGROUPS + ((v & 1023) >> 5)];
        bf16x4 o;
        o[0] = (bf16_t)((float)a.x * s);
        o[1] = (bf16_t)((float)a.y * s);
        o[2] = (bf16_t)((float)a.z * s);
        o[3] = (bf16_t)((float)a.w * s);
        ((bf16x4*)wb)[v] = o;
    }
}

// ---------------- GEMM: C = A[M,K] * B[N,K]^T + bias ----------------
// Faithful port of the verified 256^2 8-phase template (m201, 1563 TF @4k):
// BK=64 K-tiles held as 2 k-half slots of [256 rows][32 k] (16 KiB each,
// proven conflict-free swizzle + 2 async16/thread staging). 2 LDS buffers
// x 2 halves x 2 matrices = 128 KiB. 8 phases per iteration (2 K-tiles);
// each phase: {4-8 ds_read_b128 ; stage 1 half (2 global_load_lds) ;
// barrier ; lgkmcnt(0) ; setprio(1) 16 MFMA setprio(0) ; barrier}.
// vmcnt(6) ONLY at phases 4 and 8. Stage rotation: p1:A-kh1(K+1),
// p2..p5: B0/A0/B1/A1(K+2), p6..p8: B0/A0/B1(K+3).
// Ledger: vmcnt(6)@p4 keeps {p2,p3,p4} -> drains p1 and older => K-tile
// K+1 certified for p5-8; vmcnt(6)@p8 drains p5 => K+2 certified for
// next iteration's p1-4. WAR: every slot write lands >=1 barrier-pair
// after its last read's lgkmcnt(0). Tail: clamped dummy stages keep the
// loop uniform and the ledger exact.
#define BM 256
#define BN 256
#define BKH 32                  // k-half (slot) width
#define NKT (IN_F / 64)         // 64 K-tiles of 64
#define SLOTE (BM * BKH)        // 8192 bf16 = 16 KiB per slot
#define NT_M  (TOKENS / BM)     // 16
#define NT_N  (OUT_F / BN)      // 43

__device__ __forceinline__ void async16(const void* g, void* l) {
    __builtin_amdgcn_global_load_lds(
        (const __attribute__((address_space(1))) uint32_t*)g,
        (__attribute__((address_space(3))) uint32_t*)l, 16, 0, 0);
}

#define MFMA(d, a, b) d = __builtin_amdgcn_mfma_f32_16x16x32_bf16(a, b, d, 0, 0, 0)

__global__ __launch_bounds__(512, 2)
void gemm_bt_kernel(const bf16_t* __restrict__ A,
                    const bf16_t* __restrict__ B,
                    const float* __restrict__ bias,
                    float* __restrict__ C) {
    __shared__ __align__(16) bf16_t sA[4 * SLOTE];   // [buf*2+kh]
    __shared__ __align__(16) bf16_t sB[4 * SLOTE];

    // ---- XCD-rectangle walk (round-4; FETCH -32%): grid 704 = 8 x 88 ----
    const int lin = blockIdx.x;
    const int xcd = lin & 7;
    const int idx = lin >> 3;
    const int mg  = xcd >> 1;
    const int nh  = xcd & 1;
    if (nh && idx >= 84) return;
    int ml, nl;
    const int s  = idx >> 5;
    if (s < 2) { ml = (idx >> 3) & 3; nl = idx & 7; }
    else {
        const int w  = nh ? 5 : 6;
        const int lo = idx - 64;
        ml = lo / w; nl = lo - ml * w;
    }
    const int bm = (mg * 4 + ml) * BM;
    const int bn = ((nh ? 22 : 0) + s * 8 + nl) * BN;

    const int tid    = threadIdx.x;
    const int lane   = tid & 63;
    const int wave   = tid >> 6;
    const int wm     = wave >> 2;         // M-half
    const int wn     = wave & 3;          // N-quarter
    const int lane15 = lane & 15;
    const int quad   = lane >> 4;
    const int swq    = quad ^ ((lane15 >> 1) & 3);   // conflict-free (measured 0)

    int aoff[8], boff[4];
    #pragma unroll
    for (int i = 0; i < 8; ++i) {
        int mr = wm * 128 + i * 16 + lane15;
        aoff[i] = mr * BKH + swq * 8;
    }
    #pragma unroll
    for (int t = 0; t < 4; ++t) {
        int nr = wn * 64 + t * 16 + lane15;
        boff[t] = nr * BKH + swq * 8;
    }

    // staging source geometry (proven in r3/r4): 2 async16/thread per slot
    const int r0   = tid >> 2;
    const int qlog = (tid & 3) ^ ((tid >> 3) & 3);
    const bf16_t* gA0 = A + (size_t)(bm + r0) * IN_F + qlog * 8;
    const bf16_t* gA1 = A + (size_t)(bm + 128 + r0) * IN_F + qlog * 8;
    const bf16_t* gB0 = B + (size_t)(bn + r0) * IN_F + qlog * 8;
    const bf16_t* gB1 = B + (size_t)(bn + 128 + r0) * IN_F + qlog * 8;
    const int ldsP0 = wave * 512;
    const int ldsP1 = 4096 + wave * 512;

    f32x4 acc[8][4] = {};
    bf16x8 aF[4], bF[4];

    // stage one 16KB k-half slot of A or B for K-tile kt (clamped dummy at tail)
#define STG_A(kt, kh) { int c = (kt) < NKT ? (kt) : NKT - 1;                    \
        const int off = (2 * c + (kh)) * BKH;                                   \
        bf16_t* d = sA + ((((kt) & 1) << 1) + (kh)) * SLOTE;                    \
        async16(gA0 + off, d + ldsP0); async16(gA1 + off, d + ldsP1); }
#define STG_B(kt, kh) { int c = (kt) < NKT ? (kt) : NKT - 1;                    \
        const int off = (2 * c + (kh)) * BKH;                                   \
        bf16_t* d = sB + ((((kt) & 1) << 1) + (kh)) * SLOTE;                    \
        async16(gB0 + off, d + ldsP0); async16(gB1 + off, d + ldsP1); }
#define RD_A(slot, half) { const bf16_t* p_ = sA + (slot) * SLOTE;              \
        aF[0] = *(const bf16x8*)(p_ + aoff[(half)*4 + 0]);                      \
        aF[1] = *(const bf16x8*)(p_ + aoff[(half)*4 + 1]);                      \
        aF[2] = *(const bf16x8*)(p_ + aoff[(half)*4 + 2]);                      \
        aF[3] = *(const bf16x8*)(p_ + aoff[(half)*4 + 3]); }
#define RD_B(slot) { const bf16_t* p_ = sB + (slot) * SLOTE;                    \
        bF[0] = *(const bf16x8*)(p_ + boff[0]);                                 \
        bF[1] = *(const bf16x8*)(p_ + boff[1]);                                 \
        bF[2] = *(const bf16x8*)(p_ + boff[2]);                                 \
        bF[3] = *(const bf16x8*)(p_ + boff[3]); }
#define MMA16(ar) { __builtin_amdgcn_s_setprio(1);                              \
        MFMA(acc[(ar)+0][0], aF[0], bF[0]); MFMA(acc[(ar)+0][1], aF[0], bF[1]); \
        MFMA(acc[(ar)+0][2], aF[0], bF[2]); MFMA(acc[(ar)+0][3], aF[0], bF[3]); \
        MFMA(acc[(ar)+1][0], aF[1], bF[0]); MFMA(acc[(ar)+1][1], aF[1], bF[1]); \
        MFMA(acc[(ar)+1][2], aF[1], bF[2]); MFMA(acc[(ar)+1][3], aF[1], bF[3]); \
        MFMA(acc[(ar)+2][0], aF[2], bF[0]); MFMA(acc[(ar)+2][1], aF[2], bF[1]); \
        MFMA(acc[(ar)+2][2], aF[2], bF[2]); MFMA(acc[(ar)+2][3], aF[2], bF[3]); \
        MFMA(acc[(ar)+3][0], aF[3], bF[0]); MFMA(acc[(ar)+3][1], aF[3], bF[1]); \
        MFMA(acc[(ar)+3][2], aF[3], bF[2]); MFMA(acc[(ar)+3][3], aF[3], bF[3]); \
        __builtin_amdgcn_s_setprio(0); }
#define BAR1 { __builtin_amdgcn_s_barrier();                                    \
        asm volatile("s_waitcnt lgkmcnt(0)" ::: "memory");                      \
        __builtin_amdgcn_sched_barrier(0); }
#define BAR2 { __builtin_amdgcn_s_barrier(); }
#define VM6  { asm volatile("s_waitcnt vmcnt(6)" ::: "memory"); }

    // prologue: K-tile 0 (4 halves) -> vmcnt(4) -> K-tile 1's B0,A0,B1 -> vmcnt(6)
    STG_B(0, 0); STG_A(0, 0); STG_B(0, 1); STG_A(0, 1);
    asm volatile("s_waitcnt vmcnt(4)" ::: "memory");
    STG_B(1, 0); STG_A(1, 0); STG_B(1, 1);
    asm volatile("s_waitcnt vmcnt(6)" ::: "memory");   // K-tile 0 landed
    __builtin_amdgcn_s_barrier();

    for (int I = 0; I < NKT / 2; ++I) {
        const int K0 = 2 * I;
        // p1: Ktile K0, kh0, acc rows 0-3 (reads 8)
        RD_B(0); RD_A(0, 0); STG_A(K0 + 1, 1);
        BAR1; MMA16(0); BAR2;
        // p2: kh0, acc rows 4-7 (reads 4, bF reused)
        RD_A(0, 1); STG_B(K0 + 2, 0);
        BAR1; MMA16(4); BAR2;
        // p3: kh1, acc rows 0-3 (reads 8)
        RD_B(1); RD_A(1, 0); STG_A(K0 + 2, 0);
        BAR1; MMA16(0); BAR2;
        // p4: kh1, acc rows 4-7; vmcnt(6) certifies K-tile K0+1
        RD_A(1, 1); STG_B(K0 + 2, 1);
        VM6; BAR1; MMA16(4); BAR2;
        // p5: Ktile K0+1, kh0, acc rows 0-3
        RD_B(2); RD_A(2, 0); STG_A(K0 + 2, 1);
        BAR1; MMA16(0); BAR2;
        // p6: kh0, acc rows 4-7
        RD_A(2, 1); STG_B(K0 + 3, 0);
        BAR1; MMA16(4); BAR2;
        // p7: kh1, acc rows 0-3
        RD_B(3); RD_A(3, 0); STG_A(K0 + 3, 0);
        BAR1; MMA16(0); BAR2;
        // p8: kh1, acc rows 4-7; vmcnt(6) certifies K-tile K0+2
        RD_A(3, 1); STG_B(K0 + 3, 1);
        VM6; BAR1; MMA16(4); BAR2;
    }

    // drain dummy prefetches before LDS goes dead / epilogue runs
    asm volatile("s_waitcnt vmcnt(0) lgkmcnt(0)" ::: "memory");

    // epilogue: C/D layout col=lane&15, row=quad*4+reg (m89/m91-verified)
    #pragma unroll
    for (int t = 0; t < 4; ++t) {
        const int n = bn + wn * 64 + t * 16 + lane15;
        const float bj = bias[n];
        #pragma unroll
        for (int i = 0; i < 8; ++i) {
            const int m0 = bm + wm * 128 + i * 16 + quad * 4;
            #pragma unroll
            for (int r = 0; r < 4; ++r)
                C[(size_t)(m0 + r) * OUT_F + n] = acc[i][t][r] + bj;
        }
    }
}

extern "C" void kernel_launch(void* const* d_in, const int* in_sizes, int n_in,
                              void* d_out, int out_size, void* d_ws, size_t ws_size,
                              hipStream_t stream) {
    const float* x     = (const float*)d_in[0];
    const int*   w     = (const int*)d_in[1];
    const float* scale = (const float*)d_in[2];
    const float* bias  = (const float*)d_in[3];
    float* out = (float*)d_out;

    bf16_t* xb = (bf16_t*)d_ws;
    bf16_t* wb = (bf16_t*)((char*)d_ws + (size_t)TOKENS * IN_F * 2);

    prep_kernel<<<XBLK + WBLK, 256, 0, stream>>>(x, xb, w, scale, wb);
    gemm_bt_kernel<<<704, 512, 0, stream>>>(xb, wb, bias, out);
}